// Round 1
// baseline (12666.669 us; speedup 1.0000x reference)
//
#include <hip/hip_runtime.h>
#include <hip/hip_bf16.h>
#include <stdint.h>

typedef __attribute__((ext_vector_type(8))) short bf16x8;
typedef __attribute__((ext_vector_type(4))) float floatx4;

// Problem constants
#define TT 512
#define BB 64
#define DD 1024
#define HH 1024
#define N4H 4096
#define M_TOT 32768          // TT*BB
#define YS_ELEMS 33554432UL  // TT*BB*HH

// ws layout (bytes)
#define OFF_A     0UL           // A[n][m] col-major bf16: 4096*32768*2 = 256 MiB
#define OFF_XB    268435456UL   // x bf16 [32768][1024]
#define OFF_WIT   335544320UL   // WiT bf16 [4096][1024]
#define OFF_WHT   343932928UL   // WhT bf16 [4096][1024]
#define OFF_HBUF  352321536UL   // 2 x [64][1024] bf16
#define OFF_BAR   352583680UL   // barrier counter

#define NBLK 64
#define WPITCH 2064  // bytes per ldsW row (1024*2 + 16 pad -> 2-way bank aliasing = free)

__device__ __forceinline__ unsigned short f2bf(float f) {
  union { float f; unsigned u; } v; v.f = f;
  unsigned r = (v.u + 0x7fffu + ((v.u >> 16) & 1u)) >> 16;
  return (unsigned short)r;
}
__device__ __forceinline__ float bf2f(unsigned short s) {
  union { unsigned u; float f; } v; v.u = ((unsigned)s) << 16;
  return v.f;
}
__device__ __forceinline__ float sigm(float x) { return 1.0f / (1.0f + __expf(-x)); }
__device__ __forceinline__ float tanh_fast(float x) { return 1.0f - 2.0f / (1.0f + __expf(2.0f * x)); }
__device__ __forceinline__ float ap_get(uint2 p, int r) {
  unsigned u = (r < 2) ? p.x : p.y;
  return bf2f((unsigned short)(u >> ((r & 1) * 16)));
}
__device__ __forceinline__ void gload_lds16(const void* g, void* l) {
  __builtin_amdgcn_global_load_lds((const __attribute__((address_space(1))) void*)g,
                                   (__attribute__((address_space(3))) void*)l, 16, 0, 0);
}

// ---------------- fp32 -> bf16 convert (x and h0) ----------------
__global__ void convert_kernel(const float* __restrict__ x, const float* __restrict__ h0,
                               unsigned short* __restrict__ xb, unsigned short* __restrict__ hb0) {
  const long total4 = (33554432L + 65536L) / 4;
  long stride = (long)gridDim.x * blockDim.x;
  for (long i = (long)blockIdx.x * blockDim.x + threadIdx.x; i < total4; i += stride) {
    long base = i * 4;
    const float4* src;
    unsigned short* dst;
    if (base < 33554432L) { src = (const float4*)(x + base); dst = xb + base; }
    else { src = (const float4*)(h0 + (base - 33554432L)); dst = hb0 + (base - 33554432L); }
    float4 v = *src;
    uint2 p;
    p.x = (unsigned)f2bf(v.x) | ((unsigned)f2bf(v.y) << 16);
    p.y = (unsigned)f2bf(v.z) | ((unsigned)f2bf(v.w) << 16);
    *(uint2*)dst = p;
  }
}

// ---------------- transpose W [1024][4096] fp32 -> WT [4096][1024] bf16 ----------------
__global__ void transpose_kernel(const float* __restrict__ W, unsigned short* __restrict__ WT) {
  __shared__ float tile[32][33];
  int n0 = blockIdx.x * 32, k0 = blockIdx.y * 32;
  int tx = threadIdx.x & 31, ty = threadIdx.x >> 5;
#pragma unroll
  for (int r = 0; r < 4; r++)
    tile[ty + r * 8][tx] = W[(size_t)(k0 + ty + r * 8) * 4096 + n0 + tx];
  __syncthreads();
#pragma unroll
  for (int r = 0; r < 4; r++)
    WT[(size_t)(n0 + ty + r * 8) * 1024 + k0 + tx] = f2bf(tile[tx][ty + r * 8]);
}

// ---------------- Phase 1: A[m][n] = x@Wi + b, stored col-major A[n][m] bf16 ----------------
// m97 structure: 128x128 tile, BK=32, global_load_lds width 16, 4 waves 2x2.
__global__ __launch_bounds__(256) void gemm1_kernel(const unsigned short* __restrict__ xb,
                                                    const unsigned short* __restrict__ wiT,
                                                    const float* __restrict__ bias,
                                                    unsigned short* __restrict__ Aws) {
  __shared__ unsigned short ldsA[128 * 32];
  __shared__ unsigned short ldsB[128 * 32];
  int id = blockIdx.x;
  int xcd = id & 7, seq = id >> 3;
  int n0 = (xcd * 4 + (seq & 3)) * 128;   // Wi strips stay hot in per-XCD L2
  int m0 = (seq >> 2) * 128;
  int tid = threadIdx.x, w = tid >> 6, l = tid & 63;
  int wm = w & 1, wn = w >> 1;
  int c = l & 15, q = l >> 4;
  const floatx4 fz = {0.f, 0.f, 0.f, 0.f};
  floatx4 acc[4][4];
#pragma unroll
  for (int mi = 0; mi < 4; mi++)
#pragma unroll
    for (int ni = 0; ni < 4; ni++) acc[mi][ni] = fz;

  const char* gA = (const char*)xb + (size_t)(m0 + w * 32 + (l >> 2)) * 2048 + (l & 3) * 16;
  const char* gB = (const char*)wiT + (size_t)(n0 + w * 32 + (l >> 2)) * 2048 + (l & 3) * 16;
  char* lA = (char*)ldsA + (w * 32) * 64;  // wave-uniform LDS base; HW adds lane*16
  char* lB = (char*)ldsB + (w * 32) * 64;

  for (int kt = 0; kt < 32; kt++) {
    gload_lds16(gA, lA);
    gload_lds16(gA + 16 * 2048, lA + 16 * 64);
    gload_lds16(gB, lB);
    gload_lds16(gB + 16 * 2048, lB + 16 * 64);
    gA += 64; gB += 64;
    __syncthreads();  // drains vmcnt before barrier -> LDS valid
    bf16x8 a[4], b[4];
#pragma unroll
    for (int mi = 0; mi < 4; mi++)
      a[mi] = *(const bf16x8*)((const char*)ldsA + (wm * 64 + mi * 16 + c) * 64 + q * 16);
#pragma unroll
    for (int ni = 0; ni < 4; ni++)
      b[ni] = *(const bf16x8*)((const char*)ldsB + (wn * 64 + ni * 16 + c) * 64 + q * 16);
#pragma unroll
    for (int mi = 0; mi < 4; mi++)
#pragma unroll
      for (int ni = 0; ni < 4; ni++)
        acc[mi][ni] = __builtin_amdgcn_mfma_f32_16x16x32_bf16(a[mi], b[ni], acc[mi][ni], 0, 0, 0);
    __syncthreads();
  }
  // epilogue: +bias, bf16, store col-major A[n][m]
#pragma unroll
  for (int mi = 0; mi < 4; mi++) {
#pragma unroll
    for (int ni = 0; ni < 4; ni++) {
      int n_g = n0 + wn * 64 + ni * 16 + c;
      float bn = bias[n_g];
      size_t mbase = (size_t)m0 + wm * 64 + mi * 16 + q * 4;
      floatx4 v = acc[mi][ni];
      uint2 p;
      p.x = (unsigned)f2bf(v.x + bn) | ((unsigned)f2bf(v.y + bn) << 16);
      p.y = (unsigned)f2bf(v.z + bn) | ((unsigned)f2bf(v.w + bn) << 16);
      *(uint2*)((char*)Aws + (((size_t)n_g << 15) + mbase) * 2) = p;
    }
  }
}

// ---------------- Phase 2: persistent recurrent kernel, 64 blocks ----------------
// Block b owns h-cols [16b,16b+16). Wave (wi,wj): m-rows 32wi..+31, gates {2wj,2wj+1}.
__global__ __launch_bounds__(256) void lstm_kernel(const unsigned short* __restrict__ Aws,
                                                   const unsigned short* __restrict__ whT,
                                                   const float* __restrict__ c0,
                                                   unsigned short* __restrict__ hbuf,
                                                   float* __restrict__ out,
                                                   int* __restrict__ bar) {
  extern __shared__ char smem[];
  char* ldsW = smem;                            // 64 rows * WPITCH
  float* ldsG = (float*)(smem + 64 * WPITCH);   // 64x16 tanh(g)
  float* ldsO = ldsG + 1024;                    // 64x16 sigmoid(o)
  int tid = threadIdx.x, wid = tid >> 6, l = tid & 63;
  int wi = wid & 1, wj = wid >> 1;
  int c = l & 15, q = l >> 4;
  int hbase = blockIdx.x * 16;

  // stage WhT slice into LDS once (row ln -> gate=ln>>4, col=ln&15)
  for (int i = tid; i < 64 * 128; i += 256) {
    int ln = i >> 7, ch = i & 127;
    int n_g = (ln >> 4) * 1024 + hbase + (ln & 15);
    *(uint4*)(ldsW + ln * WPITCH + ch * 16) =
        *(const uint4*)((const char*)whT + (size_t)n_g * 2048 + ch * 16);
  }
  // c state in registers (only gate-pair-0 waves own it)
  float cst[2][4];
  if (wj == 0) {
#pragma unroll
    for (int mi = 0; mi < 2; mi++)
#pragma unroll
      for (int r = 0; r < 4; r++)
        cst[mi][r] = c0[(wi * 32 + mi * 16 + q * 4 + r) * 1024 + hbase + c];
  }
  __syncthreads();

  for (int t = 0; t < 512; t++) {
    const char* hp = (const char*)hbuf + (size_t)(t & 1) * 131072;
    // prefetch this step's A slice (4 bf16 per acc tile, contiguous in col-major A)
    uint2 ap[2][2];
#pragma unroll
    for (int mi = 0; mi < 2; mi++)
#pragma unroll
      for (int nj = 0; nj < 2; nj++) {
        size_t n_g = (size_t)(wj * 2 + nj) * 1024 + hbase + c;
        ap[mi][nj] = *(const uint2*)((const char*)Aws +
                      ((n_g << 15) + (size_t)t * 64 + wi * 32 + mi * 16 + q * 4) * 2);
      }
    const floatx4 fz = {0.f, 0.f, 0.f, 0.f};
    floatx4 acc[2][2] = {{fz, fz}, {fz, fz}};
#pragma unroll 4
    for (int kt = 0; kt < 32; kt++) {
      bf16x8 af[2], bw[2];
#pragma unroll
      for (int mi = 0; mi < 2; mi++)
        af[mi] = *(const bf16x8*)(hp + (size_t)(wi * 32 + mi * 16 + c) * 2048 + kt * 64 + q * 16);
#pragma unroll
      for (int nj = 0; nj < 2; nj++)
        bw[nj] = *(const bf16x8*)(ldsW + (wj * 32 + nj * 16 + c) * WPITCH + kt * 64 + q * 16);
#pragma unroll
      for (int mi = 0; mi < 2; mi++)
#pragma unroll
        for (int nj = 0; nj < 2; nj++)
          acc[mi][nj] = __builtin_amdgcn_mfma_f32_16x16x32_bf16(af[mi], bw[nj], acc[mi][nj], 0, 0, 0);
    }
    // epilogue: gate-pair 1 (g,o) publishes through LDS
    if (wj == 1) {
#pragma unroll
      for (int mi = 0; mi < 2; mi++)
#pragma unroll
        for (int r = 0; r < 4; r++) {
          int row = wi * 32 + mi * 16 + q * 4 + r;
          float zg = acc[mi][0][r] + ap_get(ap[mi][0], r);
          float zo = acc[mi][1][r] + ap_get(ap[mi][1], r);
          ldsG[row * 16 + c] = tanh_fast(zg);
          ldsO[row * 16 + c] = sigm(zo);
        }
    }
    __syncthreads();
    if (wj == 0) {
#pragma unroll
      for (int mi = 0; mi < 2; mi++)
#pragma unroll
        for (int r = 0; r < 4; r++) {
          int row = wi * 32 + mi * 16 + q * 4 + r;
          float zi = acc[mi][0][r] + ap_get(ap[mi][0], r);
          float zf = acc[mi][1][r] + ap_get(ap[mi][1], r);
          float ig = sigm(zi), fg = sigm(zf);
          float tg = ldsG[row * 16 + c], og = ldsO[row * 16 + c];
          float cn = fg * cst[mi][r] + ig * tg;
          cst[mi][r] = cn;
          float h = og * tanh_fast(cn);
          hbuf[(size_t)(1 - (t & 1)) * 65536 + row * 1024 + hbase + c] = f2bf(h);
          out[(size_t)t * 65536 + row * 1024 + hbase + c] = h;
          if (t == 511) {
            out[YS_ELEMS + (size_t)row * 1024 + hbase + c] = cn;          // cT
            out[YS_ELEMS + 65536 + (size_t)row * 1024 + hbase + c] = h;   // hT
          }
        }
    }
    // grid barrier (agent scope; all 64 blocks co-resident at 1 block/CU)
    __threadfence();
    __syncthreads();
    if (t < 511) {
      if (tid == 0) {
        __hip_atomic_fetch_add(bar, 1, __ATOMIC_ACQ_REL, __HIP_MEMORY_SCOPE_AGENT);
        int target = NBLK * (t + 1);
        while (__hip_atomic_load(bar, __ATOMIC_ACQUIRE, __HIP_MEMORY_SCOPE_AGENT) < target)
          __builtin_amdgcn_s_sleep(2);
      }
      __syncthreads();
    }
  }
}

extern "C" void kernel_launch(void* const* d_in, const int* in_sizes, int n_in,
                              void* d_out, int out_size, void* d_ws, size_t ws_size,
                              hipStream_t stream) {
  (void)in_sizes; (void)n_in; (void)out_size; (void)ws_size;
  const float* x  = (const float*)d_in[0];
  const float* c0 = (const float*)d_in[1];
  const float* h0 = (const float*)d_in[2];
  const float* Wi = (const float*)d_in[3];
  const float* Wh = (const float*)d_in[4];
  const float* b  = (const float*)d_in[5];
  float* out = (float*)d_out;
  char* ws = (char*)d_ws;
  unsigned short* Aws  = (unsigned short*)(ws + OFF_A);
  unsigned short* xb   = (unsigned short*)(ws + OFF_XB);
  unsigned short* wiT  = (unsigned short*)(ws + OFF_WIT);
  unsigned short* whT  = (unsigned short*)(ws + OFF_WHT);
  unsigned short* hbuf = (unsigned short*)(ws + OFF_HBUF);
  int* bar = (int*)(ws + OFF_BAR);

  hipMemsetAsync(bar, 0, 64, stream);
  convert_kernel<<<4096, 256, 0, stream>>>(x, h0, xb, hbuf);
  transpose_kernel<<<dim3(128, 32), 256, 0, stream>>>(Wi, wiT);
  transpose_kernel<<<dim3(128, 32), 256, 0, stream>>>(Wh, whT);
  gemm1_kernel<<<8192, 256, 0, stream>>>(xb, wiT, b, Aws);
  lstm_kernel<<<NBLK, 256, 64 * WPITCH + 8192, stream>>>(Aws, whT, c0, hbuf, out, bar);
}

// Round 2
// 10878.237 us; speedup vs baseline: 1.1644x; 1.1644x over previous
//
#include <hip/hip_runtime.h>
#include <hip/hip_bf16.h>
#include <stdint.h>

typedef __attribute__((ext_vector_type(8))) short bf16x8;
typedef __attribute__((ext_vector_type(4))) float floatx4;

// Problem constants
#define TT 512
#define BB 64
#define DD 1024
#define HH 1024
#define N4H 4096
#define M_TOT 32768          // TT*BB
#define YS_ELEMS 33554432UL  // TT*BB*HH

// ws layout (bytes)
#define OFF_A     0UL           // A[n][m] col-major bf16: 4096*32768*2 = 256 MiB
#define OFF_XB    268435456UL   // x bf16 [32768][1024]
#define OFF_WIT   335544320UL   // WiT bf16 [4096][1024]
#define OFF_WHT   343932928UL   // WhT bf16 [4096][1024]
#define OFF_HBUF  352321536UL   // 2 x [64][1024] bf16
#define OFF_FLAGS 352583680UL   // 64 flags, 64B stride = 4 KiB

#define NBLK 64
#define WPITCH 2064  // bytes per ldsW row

__device__ __forceinline__ unsigned short f2bf(float f) {
  union { float f; unsigned u; } v; v.f = f;
  unsigned r = (v.u + 0x7fffu + ((v.u >> 16) & 1u)) >> 16;
  return (unsigned short)r;
}
__device__ __forceinline__ float bf2f(unsigned short s) {
  union { unsigned u; float f; } v; v.u = ((unsigned)s) << 16;
  return v.f;
}
__device__ __forceinline__ float sigm(float x) { return 1.0f / (1.0f + __expf(-x)); }
__device__ __forceinline__ float tanh_fast(float x) { return 1.0f - 2.0f / (1.0f + __expf(2.0f * x)); }
__device__ __forceinline__ float ap_get(uint2 p, int r) {
  unsigned u = (r < 2) ? p.x : p.y;
  return bf2f((unsigned short)(u >> ((r & 1) * 16)));
}
__device__ __forceinline__ void gload_lds16(const void* g, void* l) {
  __builtin_amdgcn_global_load_lds((const __attribute__((address_space(1))) void*)g,
                                   (__attribute__((address_space(3))) void*)l, 16, 0, 0);
}

// ---------------- fp32 -> bf16 convert (x and h0) ----------------
__global__ void convert_kernel(const float* __restrict__ x, const float* __restrict__ h0,
                               unsigned short* __restrict__ xb, unsigned short* __restrict__ hb0) {
  const long total4 = (33554432L + 65536L) / 4;
  long stride = (long)gridDim.x * blockDim.x;
  for (long i = (long)blockIdx.x * blockDim.x + threadIdx.x; i < total4; i += stride) {
    long base = i * 4;
    const float4* src;
    unsigned short* dst;
    if (base < 33554432L) { src = (const float4*)(x + base); dst = xb + base; }
    else { src = (const float4*)(h0 + (base - 33554432L)); dst = hb0 + (base - 33554432L); }
    float4 v = *src;
    uint2 p;
    p.x = (unsigned)f2bf(v.x) | ((unsigned)f2bf(v.y) << 16);
    p.y = (unsigned)f2bf(v.z) | ((unsigned)f2bf(v.w) << 16);
    *(uint2*)dst = p;
  }
}

// ---------------- transpose W [1024][4096] fp32 -> WT [4096][1024] bf16 ----------------
__global__ void transpose_kernel(const float* __restrict__ W, unsigned short* __restrict__ WT) {
  __shared__ float tile[32][33];
  int n0 = blockIdx.x * 32, k0 = blockIdx.y * 32;
  int tx = threadIdx.x & 31, ty = threadIdx.x >> 5;
#pragma unroll
  for (int r = 0; r < 4; r++)
    tile[ty + r * 8][tx] = W[(size_t)(k0 + ty + r * 8) * 4096 + n0 + tx];
  __syncthreads();
#pragma unroll
  for (int r = 0; r < 4; r++)
    WT[(size_t)(n0 + ty + r * 8) * 1024 + k0 + tx] = f2bf(tile[tx][ty + r * 8]);
}

// ---------------- Phase 1: A[m][n] = x@Wi + b, stored col-major A[n][m] bf16 ----------------
__global__ __launch_bounds__(256) void gemm1_kernel(const unsigned short* __restrict__ xb,
                                                    const unsigned short* __restrict__ wiT,
                                                    const float* __restrict__ bias,
                                                    unsigned short* __restrict__ Aws) {
  __shared__ unsigned short ldsA[128 * 32];
  __shared__ unsigned short ldsB[128 * 32];
  int id = blockIdx.x;
  int xcd = id & 7, seq = id >> 3;
  int n0 = (xcd * 4 + (seq & 3)) * 128;
  int m0 = (seq >> 2) * 128;
  int tid = threadIdx.x, w = tid >> 6, l = tid & 63;
  int wm = w & 1, wn = w >> 1;
  int c = l & 15, q = l >> 4;
  const floatx4 fz = {0.f, 0.f, 0.f, 0.f};
  floatx4 acc[4][4];
#pragma unroll
  for (int mi = 0; mi < 4; mi++)
#pragma unroll
    for (int ni = 0; ni < 4; ni++) acc[mi][ni] = fz;

  const char* gA = (const char*)xb + (size_t)(m0 + w * 32 + (l >> 2)) * 2048 + (l & 3) * 16;
  const char* gB = (const char*)wiT + (size_t)(n0 + w * 32 + (l >> 2)) * 2048 + (l & 3) * 16;
  char* lA = (char*)ldsA + (w * 32) * 64;
  char* lB = (char*)ldsB + (w * 32) * 64;

  for (int kt = 0; kt < 32; kt++) {
    gload_lds16(gA, lA);
    gload_lds16(gA + 16 * 2048, lA + 16 * 64);
    gload_lds16(gB, lB);
    gload_lds16(gB + 16 * 2048, lB + 16 * 64);
    gA += 64; gB += 64;
    __syncthreads();
    bf16x8 a[4], b[4];
#pragma unroll
    for (int mi = 0; mi < 4; mi++)
      a[mi] = *(const bf16x8*)((const char*)ldsA + (wm * 64 + mi * 16 + c) * 64 + q * 16);
#pragma unroll
    for (int ni = 0; ni < 4; ni++)
      b[ni] = *(const bf16x8*)((const char*)ldsB + (wn * 64 + ni * 16 + c) * 64 + q * 16);
#pragma unroll
    for (int mi = 0; mi < 4; mi++)
#pragma unroll
      for (int ni = 0; ni < 4; ni++)
        acc[mi][ni] = __builtin_amdgcn_mfma_f32_16x16x32_bf16(a[mi], b[ni], acc[mi][ni], 0, 0, 0);
    __syncthreads();
  }
#pragma unroll
  for (int mi = 0; mi < 4; mi++) {
#pragma unroll
    for (int ni = 0; ni < 4; ni++) {
      int n_g = n0 + wn * 64 + ni * 16 + c;
      float bn = bias[n_g];
      size_t mbase = (size_t)m0 + wm * 64 + mi * 16 + q * 4;
      floatx4 v = acc[mi][ni];
      uint2 p;
      p.x = (unsigned)f2bf(v.x + bn) | ((unsigned)f2bf(v.y + bn) << 16);
      p.y = (unsigned)f2bf(v.z + bn) | ((unsigned)f2bf(v.w + bn) << 16);
      *(uint2*)((char*)Aws + (((size_t)n_g << 15) + mbase) * 2) = p;
    }
  }
}

// ---------------- Phase 2: persistent recurrent kernel, 64 blocks ----------------
// Sync design (R2): per-block padded flags; relaxed wave-parallel spin (no cache
// maintenance per probe); ONE acquire (buffer_inv) per step per block; ONE
// release flag store (buffer_wbl2) per step per block. No __threadfence().
__global__ __launch_bounds__(256) void lstm_kernel(const unsigned short* __restrict__ Aws,
                                                   const unsigned short* __restrict__ whT,
                                                   const float* __restrict__ c0,
                                                   unsigned short* __restrict__ hbuf,
                                                   float* __restrict__ out,
                                                   int* __restrict__ flags) {
  extern __shared__ char smem[];
  char* ldsW = smem;                            // 64 rows * WPITCH
  float* ldsG = (float*)(smem + 64 * WPITCH);   // 64x16 tanh(g)
  float* ldsO = ldsG + 1024;                    // 64x16 sigmoid(o)
  int tid = threadIdx.x, wid = tid >> 6, l = tid & 63;
  int wi = wid & 1, wj = wid >> 1;
  int c = l & 15, q = l >> 4;
  int hbase = blockIdx.x * 16;

  // stage WhT slice into LDS once
  for (int i = tid; i < 64 * 128; i += 256) {
    int ln = i >> 7, ch = i & 127;
    int n_g = (ln >> 4) * 1024 + hbase + (ln & 15);
    *(uint4*)(ldsW + ln * WPITCH + ch * 16) =
        *(const uint4*)((const char*)whT + (size_t)n_g * 2048 + ch * 16);
  }
  float cst[2][4];
  if (wj == 0) {
#pragma unroll
    for (int mi = 0; mi < 2; mi++)
#pragma unroll
      for (int r = 0; r < 4; r++)
        cst[mi][r] = c0[(wi * 32 + mi * 16 + q * 4 + r) * 1024 + hbase + c];
  }
  __syncthreads();

  for (int t = 0; t < 512; t++) {
    // A-slice prefetch FIRST: in flight during the flag wait
    uint2 ap[2][2];
#pragma unroll
    for (int mi = 0; mi < 2; mi++)
#pragma unroll
      for (int nj = 0; nj < 2; nj++) {
        size_t n_g = (size_t)(wj * 2 + nj) * 1024 + hbase + c;
        ap[mi][nj] = *(const uint2*)((const char*)Aws +
                      ((n_g << 15) + (size_t)t * 64 + wi * 32 + mi * 16 + q * 4) * 2);
      }

    // wait for all blocks to have published h_t (flags >= t); t=0 passes at once
    if (wid == 0) {
      int probes = 0;
      for (;;) {
        int v = __hip_atomic_load(&flags[l * 16], __ATOMIC_RELAXED, __HIP_MEMORY_SCOPE_AGENT);
        if (__all(v >= t)) break;
        if (((++probes) & 63) == 0)
          (void)__hip_atomic_load(&flags[l * 16], __ATOMIC_ACQUIRE, __HIP_MEMORY_SCOPE_AGENT);
        __builtin_amdgcn_s_sleep(1);
      }
      // one acquire: orders subsequent h reads, invalidates stale L1/L2 lines
      (void)__hip_atomic_load(&flags[0], __ATOMIC_ACQUIRE, __HIP_MEMORY_SCOPE_AGENT);
    }
    __syncthreads();

    const char* hp = (const char*)hbuf + (size_t)(t & 1) * 131072;
    const floatx4 fz = {0.f, 0.f, 0.f, 0.f};
    floatx4 acc[2][2] = {{fz, fz}, {fz, fz}};
#pragma unroll 4
    for (int kt = 0; kt < 32; kt++) {
      bf16x8 af[2], bw[2];
#pragma unroll
      for (int mi = 0; mi < 2; mi++)
        af[mi] = *(const bf16x8*)(hp + (size_t)(wi * 32 + mi * 16 + c) * 2048 + kt * 64 + q * 16);
#pragma unroll
      for (int nj = 0; nj < 2; nj++)
        bw[nj] = *(const bf16x8*)(ldsW + (wj * 32 + nj * 16 + c) * WPITCH + kt * 64 + q * 16);
#pragma unroll
      for (int mi = 0; mi < 2; mi++)
#pragma unroll
        for (int nj = 0; nj < 2; nj++)
          acc[mi][nj] = __builtin_amdgcn_mfma_f32_16x16x32_bf16(af[mi], bw[nj], acc[mi][nj], 0, 0, 0);
    }
    // epilogue: gate-pair 1 (g,o) publishes through LDS
    if (wj == 1) {
#pragma unroll
      for (int mi = 0; mi < 2; mi++)
#pragma unroll
        for (int r = 0; r < 4; r++) {
          int row = wi * 32 + mi * 16 + q * 4 + r;
          float zg = acc[mi][0][r] + ap_get(ap[mi][0], r);
          float zo = acc[mi][1][r] + ap_get(ap[mi][1], r);
          ldsG[row * 16 + c] = tanh_fast(zg);
          ldsO[row * 16 + c] = sigm(zo);
        }
    }
    __syncthreads();
    if (wj == 0) {
#pragma unroll
      for (int mi = 0; mi < 2; mi++)
#pragma unroll
        for (int r = 0; r < 4; r++) {
          int row = wi * 32 + mi * 16 + q * 4 + r;
          float zi = acc[mi][0][r] + ap_get(ap[mi][0], r);
          float zf = acc[mi][1][r] + ap_get(ap[mi][1], r);
          float ig = sigm(zi), fg = sigm(zf);
          float tg = ldsG[row * 16 + c], og = ldsO[row * 16 + c];
          float cn = fg * cst[mi][r] + ig * tg;
          cst[mi][r] = cn;
          float h = og * tanh_fast(cn);
          hbuf[(size_t)(1 - (t & 1)) * 65536 + row * 1024 + hbase + c] = f2bf(h);
          out[(size_t)t * 65536 + row * 1024 + hbase + c] = h;
          if (t == 511) {
            out[YS_ELEMS + (size_t)row * 1024 + hbase + c] = cn;          // cT
            out[YS_ELEMS + 65536 + (size_t)row * 1024 + hbase + c] = h;   // hT
          }
        }
    }
    // publish: barrier drains all waves' stores to L2, then one release store
    __syncthreads();
    if (t < 511 && tid == 0)
      __hip_atomic_store(&flags[blockIdx.x * 16], t + 1, __ATOMIC_RELEASE, __HIP_MEMORY_SCOPE_AGENT);
  }
}

extern "C" void kernel_launch(void* const* d_in, const int* in_sizes, int n_in,
                              void* d_out, int out_size, void* d_ws, size_t ws_size,
                              hipStream_t stream) {
  (void)in_sizes; (void)n_in; (void)out_size; (void)ws_size;
  const float* x  = (const float*)d_in[0];
  const float* c0 = (const float*)d_in[1];
  const float* h0 = (const float*)d_in[2];
  const float* Wi = (const float*)d_in[3];
  const float* Wh = (const float*)d_in[4];
  const float* b  = (const float*)d_in[5];
  float* out = (float*)d_out;
  char* ws = (char*)d_ws;
  unsigned short* Aws  = (unsigned short*)(ws + OFF_A);
  unsigned short* xb   = (unsigned short*)(ws + OFF_XB);
  unsigned short* wiT  = (unsigned short*)(ws + OFF_WIT);
  unsigned short* whT  = (unsigned short*)(ws + OFF_WHT);
  unsigned short* hbuf = (unsigned short*)(ws + OFF_HBUF);
  int* flags = (int*)(ws + OFF_FLAGS);

  hipMemsetAsync(flags, 0, 4096, stream);
  convert_kernel<<<4096, 256, 0, stream>>>(x, h0, xb, hbuf);
  transpose_kernel<<<dim3(128, 32), 256, 0, stream>>>(Wi, wiT);
  transpose_kernel<<<dim3(128, 32), 256, 0, stream>>>(Wh, whT);
  gemm1_kernel<<<8192, 256, 0, stream>>>(xb, wiT, b, Aws);
  lstm_kernel<<<NBLK, 256, 64 * WPITCH + 8192, stream>>>(Aws, whT, c0, hbuf, out, flags);
}

// Round 3
// 6585.596 us; speedup vs baseline: 1.9234x; 1.6518x over previous
//
#include <hip/hip_runtime.h>
#include <hip/hip_bf16.h>
#include <stdint.h>

typedef __attribute__((ext_vector_type(8))) short bf16x8;
typedef __attribute__((ext_vector_type(4))) float floatx4;

// Problem constants
#define TT 512
#define BB 64
#define DD 1024
#define HH 1024
#define YS_ELEMS 33554432UL  // TT*BB*HH

// ws layout (bytes)
#define OFF_A     0UL           // A[n][m] col-major bf16: 4096*32768*2 = 256 MiB
#define OFF_XB    268435456UL   // x bf16 [32768][1024]
#define OFF_WIT   335544320UL   // WiT bf16 [4096][1024]
#define OFF_WHT   343932928UL   // WhT bf16 [4096][1024]
#define OFF_HBUF  352321536UL   // 2 x [64][1024] bf16
#define OFF_FLAGS 352583680UL   // 64 flags, 64B stride

#define NBLK 64
#define WPITCH 2064

__device__ __forceinline__ unsigned short f2bf(float f) {
  union { float f; unsigned u; } v; v.f = f;
  unsigned r = (v.u + 0x7fffu + ((v.u >> 16) & 1u)) >> 16;
  return (unsigned short)r;
}
__device__ __forceinline__ float bf2f(unsigned short s) {
  union { unsigned u; float f; } v; v.u = ((unsigned)s) << 16;
  return v.f;
}
__device__ __forceinline__ float sigm(float x) { return 1.0f / (1.0f + __expf(-x)); }
__device__ __forceinline__ float tanh_fast(float x) { return 1.0f - 2.0f / (1.0f + __expf(2.0f * x)); }
__device__ __forceinline__ float ap_get(uint2 p, int r) {
  unsigned u = (r < 2) ? p.x : p.y;
  return bf2f((unsigned short)(u >> ((r & 1) * 16)));
}
__device__ __forceinline__ void gload_lds16(const void* g, void* l) {
  __builtin_amdgcn_global_load_lds((const __attribute__((address_space(1))) void*)g,
                                   (__attribute__((address_space(3))) void*)l, 16, 0, 0);
}
// ---- Infinity-Cache-coherent (bypass L1+L2) asm memory ops ----
__device__ __forceinline__ bf16x8 ldg_b128_if(const void* p) {
  bf16x8 v;
  asm volatile("global_load_dwordx4 %0, %1, off sc0 sc1"
               : "=v"(v) : "v"(p) : "memory");
  return v;
}
__device__ __forceinline__ int ldg_b32_if(const void* p) {
  int v;
  asm volatile("global_load_dword %0, %1, off sc0 sc1\n\ts_waitcnt vmcnt(0)"
               : "=v"(v) : "v"(p) : "memory");
  return v;
}
__device__ __forceinline__ void stg_b64_if(void* p, uint2 v) {
  asm volatile("global_store_dwordx2 %0, %1, off sc0 sc1"
               :: "v"(p), "v"(v) : "memory");
}
__device__ __forceinline__ void stg_b32_if(void* p, int v) {
  asm volatile("global_store_dword %0, %1, off sc0 sc1"
               :: "v"(p), "v"(v) : "memory");
}

// ---------------- fp32 -> bf16 convert (x and h0) ----------------
__global__ void convert_kernel(const float* __restrict__ x, const float* __restrict__ h0,
                               unsigned short* __restrict__ xb, unsigned short* __restrict__ hb0) {
  const long total4 = (33554432L + 65536L) / 4;
  long stride = (long)gridDim.x * blockDim.x;
  for (long i = (long)blockIdx.x * blockDim.x + threadIdx.x; i < total4; i += stride) {
    long base = i * 4;
    const float4* src;
    unsigned short* dst;
    if (base < 33554432L) { src = (const float4*)(x + base); dst = xb + base; }
    else { src = (const float4*)(h0 + (base - 33554432L)); dst = hb0 + (base - 33554432L); }
    float4 v = *src;
    uint2 p;
    p.x = (unsigned)f2bf(v.x) | ((unsigned)f2bf(v.y) << 16);
    p.y = (unsigned)f2bf(v.z) | ((unsigned)f2bf(v.w) << 16);
    *(uint2*)dst = p;
  }
}

// ---------------- transpose W [1024][4096] fp32 -> WT [4096][1024] bf16 ----------------
__global__ void transpose_kernel(const float* __restrict__ W, unsigned short* __restrict__ WT) {
  __shared__ float tile[32][33];
  int n0 = blockIdx.x * 32, k0 = blockIdx.y * 32;
  int tx = threadIdx.x & 31, ty = threadIdx.x >> 5;
#pragma unroll
  for (int r = 0; r < 4; r++)
    tile[ty + r * 8][tx] = W[(size_t)(k0 + ty + r * 8) * 4096 + n0 + tx];
  __syncthreads();
#pragma unroll
  for (int r = 0; r < 4; r++)
    WT[(size_t)(n0 + ty + r * 8) * 1024 + k0 + tx] = f2bf(tile[tx][ty + r * 8]);
}

// ---------------- Phase 1: A[m][n] = x@Wi + b, stored col-major A[n][m] bf16 ----------------
__global__ __launch_bounds__(256) void gemm1_kernel(const unsigned short* __restrict__ xb,
                                                    const unsigned short* __restrict__ wiT,
                                                    const float* __restrict__ bias,
                                                    unsigned short* __restrict__ Aws) {
  __shared__ unsigned short ldsA[128 * 32];
  __shared__ unsigned short ldsB[128 * 32];
  int id = blockIdx.x;
  int xcd = id & 7, seq = id >> 3;
  int n0 = (xcd * 4 + (seq & 3)) * 128;
  int m0 = (seq >> 2) * 128;
  int tid = threadIdx.x, w = tid >> 6, l = tid & 63;
  int wm = w & 1, wn = w >> 1;
  int c = l & 15, q = l >> 4;
  const floatx4 fz = {0.f, 0.f, 0.f, 0.f};
  floatx4 acc[4][4];
#pragma unroll
  for (int mi = 0; mi < 4; mi++)
#pragma unroll
    for (int ni = 0; ni < 4; ni++) acc[mi][ni] = fz;

  const char* gA = (const char*)xb + (size_t)(m0 + w * 32 + (l >> 2)) * 2048 + (l & 3) * 16;
  const char* gB = (const char*)wiT + (size_t)(n0 + w * 32 + (l >> 2)) * 2048 + (l & 3) * 16;
  char* lA = (char*)ldsA + (w * 32) * 64;
  char* lB = (char*)ldsB + (w * 32) * 64;

  for (int kt = 0; kt < 32; kt++) {
    gload_lds16(gA, lA);
    gload_lds16(gA + 16 * 2048, lA + 16 * 64);
    gload_lds16(gB, lB);
    gload_lds16(gB + 16 * 2048, lB + 16 * 64);
    gA += 64; gB += 64;
    __syncthreads();
    bf16x8 a[4], b[4];
#pragma unroll
    for (int mi = 0; mi < 4; mi++)
      a[mi] = *(const bf16x8*)((const char*)ldsA + (wm * 64 + mi * 16 + c) * 64 + q * 16);
#pragma unroll
    for (int ni = 0; ni < 4; ni++)
      b[ni] = *(const bf16x8*)((const char*)ldsB + (wn * 64 + ni * 16 + c) * 64 + q * 16);
#pragma unroll
    for (int mi = 0; mi < 4; mi++)
#pragma unroll
      for (int ni = 0; ni < 4; ni++)
        acc[mi][ni] = __builtin_amdgcn_mfma_f32_16x16x32_bf16(a[mi], b[ni], acc[mi][ni], 0, 0, 0);
    __syncthreads();
  }
#pragma unroll
  for (int mi = 0; mi < 4; mi++) {
#pragma unroll
    for (int ni = 0; ni < 4; ni++) {
      int n_g = n0 + wn * 64 + ni * 16 + c;
      float bn = bias[n_g];
      size_t mbase = (size_t)m0 + wm * 64 + mi * 16 + q * 4;
      floatx4 v = acc[mi][ni];
      uint2 p;
      p.x = (unsigned)f2bf(v.x + bn) | ((unsigned)f2bf(v.y + bn) << 16);
      p.y = (unsigned)f2bf(v.z + bn) | ((unsigned)f2bf(v.w + bn) << 16);
      *(uint2*)((char*)Aws + (((size_t)n_g << 15) + mbase) * 2) = p;
    }
  }
}

// ---------------- Phase 2: persistent recurrent kernel, 64 blocks ----------------
// R3 sync: ALL cross-block data (h, flags) moves with sc0 sc1 (bypass L1+L2,
// coherent at Infinity Cache). No buffer_wbl2 / buffer_inv anywhere in the loop.
__global__ __launch_bounds__(256) void lstm_kernel(const unsigned short* __restrict__ Aws,
                                                   const unsigned short* __restrict__ whT,
                                                   const float* __restrict__ c0,
                                                   unsigned short* __restrict__ hbuf,
                                                   float* __restrict__ out,
                                                   int* __restrict__ flags) {
  extern __shared__ char smem[];
  char* ldsW = smem;                            // 64 rows * WPITCH
  float* ldsG = (float*)(smem + 64 * WPITCH);   // 64x16 tanh(g)
  float* ldsO = ldsG + 1024;                    // 64x16 sigmoid(o), then reused for h
  int tid = threadIdx.x, wid = tid >> 6, l = tid & 63;
  int wi = wid & 1, wj = wid >> 1;
  int c = l & 15, q = l >> 4;
  int hbase = blockIdx.x * 16;

  // stage WhT slice into LDS once
  for (int i = tid; i < 64 * 128; i += 256) {
    int ln = i >> 7, ch = i & 127;
    int n_g = (ln >> 4) * 1024 + hbase + (ln & 15);
    *(uint4*)(ldsW + ln * WPITCH + ch * 16) =
        *(const uint4*)((const char*)whT + (size_t)n_g * 2048 + ch * 16);
  }
  float cst[2][4];
  if (wj == 0) {
#pragma unroll
    for (int mi = 0; mi < 2; mi++)
#pragma unroll
      for (int r = 0; r < 4; r++)
        cst[mi][r] = c0[(wi * 32 + mi * 16 + q * 4 + r) * 1024 + hbase + c];
  }
  __syncthreads();

  for (int t = 0; t < 512; t++) {
    // A-slice prefetch (cached loads; A is static, written by gemm1)
    uint2 ap[2][2];
#pragma unroll
    for (int mi = 0; mi < 2; mi++)
#pragma unroll
      for (int nj = 0; nj < 2; nj++) {
        size_t n_g = (size_t)(wj * 2 + nj) * 1024 + hbase + c;
        ap[mi][nj] = *(const uint2*)((const char*)Aws +
                      ((n_g << 15) + (size_t)t * 64 + wi * 32 + mi * 16 + q * 4) * 2);
      }

    // wave 0: poll flags (IF-coherent loads, no cache maintenance)
    if (wid == 0) {
      const char* fp_ = (const char*)(flags + l * 16);
      int probes = 0;
      for (;;) {
        int v = ldg_b32_if(fp_);
        if (__all(v >= t)) break;
        if (((++probes) & 2047) == 0)  // safety valve only
          (void)__hip_atomic_load(&flags[l * 16], __ATOMIC_ACQUIRE, __HIP_MEMORY_SCOPE_AGENT);
      }
    }
    __syncthreads();

    // K-loop: h from IF via sc0sc1 loads, depth-8 software pipeline
    const char* hp = (const char*)hbuf + (size_t)(t & 1) * 131072;
    const char* ha0 = hp + (size_t)(wi * 32 + c) * 2048 + q * 16;
    const char* ha1 = ha0 + 16 * 2048;
    bf16x8 pf[8][2];
#pragma unroll
    for (int d = 0; d < 8; d++) {
      pf[d][0] = ldg_b128_if(ha0 + d * 64);
      pf[d][1] = ldg_b128_if(ha1 + d * 64);
    }
    const floatx4 fz = {0.f, 0.f, 0.f, 0.f};
    floatx4 acc[2][2] = {{fz, fz}, {fz, fz}};
#pragma unroll
    for (int kt = 0; kt < 32; kt++) {
      const int slot = kt & 7;
      if (kt < 24) asm volatile("s_waitcnt vmcnt(14)" ::: "memory");
      else if (kt == 24) asm volatile("s_waitcnt vmcnt(0)" ::: "memory");
      bf16x8 a0 = pf[slot][0], a1 = pf[slot][1];  // copy: WAR-safe vs reload
      if (kt + 8 < 32) {
        pf[slot][0] = ldg_b128_if(ha0 + (kt + 8) * 64);
        pf[slot][1] = ldg_b128_if(ha1 + (kt + 8) * 64);
      }
      bf16x8 b0 = *(const bf16x8*)(ldsW + (wj * 32 + 0 * 16 + c) * WPITCH + kt * 64 + q * 16);
      bf16x8 b1 = *(const bf16x8*)(ldsW + (wj * 32 + 1 * 16 + c) * WPITCH + kt * 64 + q * 16);
      acc[0][0] = __builtin_amdgcn_mfma_f32_16x16x32_bf16(a0, b0, acc[0][0], 0, 0, 0);
      acc[0][1] = __builtin_amdgcn_mfma_f32_16x16x32_bf16(a0, b1, acc[0][1], 0, 0, 0);
      acc[1][0] = __builtin_amdgcn_mfma_f32_16x16x32_bf16(a1, b0, acc[1][0], 0, 0, 0);
      acc[1][1] = __builtin_amdgcn_mfma_f32_16x16x32_bf16(a1, b1, acc[1][1], 0, 0, 0);
    }

    // epilogue: gate-pair 1 (g,o) publishes through LDS
    if (wj == 1) {
#pragma unroll
      for (int mi = 0; mi < 2; mi++)
#pragma unroll
        for (int r = 0; r < 4; r++) {
          int row = wi * 32 + mi * 16 + q * 4 + r;
          float zg = acc[mi][0][r] + ap_get(ap[mi][0], r);
          float zo = acc[mi][1][r] + ap_get(ap[mi][1], r);
          ldsG[row * 16 + c] = tanh_fast(zg);
          ldsO[row * 16 + c] = sigm(zo);
        }
    }
    __syncthreads();
    if (wj == 0) {
#pragma unroll
      for (int mi = 0; mi < 2; mi++)
#pragma unroll
        for (int r = 0; r < 4; r++) {
          int row = wi * 32 + mi * 16 + q * 4 + r;
          float zi = acc[mi][0][r] + ap_get(ap[mi][0], r);
          float zf = acc[mi][1][r] + ap_get(ap[mi][1], r);
          float ig = sigm(zi), fg = sigm(zf);
          float tg = ldsG[row * 16 + c], og = ldsO[row * 16 + c];
          float cn = fg * cst[mi][r] + ig * tg;
          cst[mi][r] = cn;
          float h = og * tanh_fast(cn);
          ldsO[row * 16 + c] = h;  // in-place: this slot is owned by this thread
          out[(size_t)t * 65536 + row * 1024 + hbase + c] = h;
          if (t == 511) {
            out[YS_ELEMS + (size_t)row * 1024 + hbase + c] = cn;          // cT
            out[YS_ELEMS + 65536 + (size_t)row * 1024 + hbase + c] = h;   // hT
          }
        }
    }
    __syncthreads();
    // pack h -> hbuf[next] with IF-coherent stores; all threads
    if (t < 511) {
      unsigned short* hn = hbuf + (size_t)(1 - (t & 1)) * 65536;
      int row = tid >> 2, c4 = (tid & 3) * 4;
      float v0 = ldsO[row * 16 + c4 + 0], v1 = ldsO[row * 16 + c4 + 1];
      float v2 = ldsO[row * 16 + c4 + 2], v3 = ldsO[row * 16 + c4 + 3];
      uint2 pk;
      pk.x = (unsigned)f2bf(v0) | ((unsigned)f2bf(v1) << 16);
      pk.y = (unsigned)f2bf(v2) | ((unsigned)f2bf(v3) << 16);
      stg_b64_if((char*)(hn + row * 1024 + hbase + c4), pk);
      asm volatile("s_waitcnt vmcnt(0)" ::: "memory");  // h acked at IF
    }
    __syncthreads();  // all waves' h stores complete before flag
    if (t < 511 && tid == 0)
      stg_b32_if(flags + blockIdx.x * 16, t + 1);
  }
}

extern "C" void kernel_launch(void* const* d_in, const int* in_sizes, int n_in,
                              void* d_out, int out_size, void* d_ws, size_t ws_size,
                              hipStream_t stream) {
  (void)in_sizes; (void)n_in; (void)out_size; (void)ws_size;
  const float* x  = (const float*)d_in[0];
  const float* c0 = (const float*)d_in[1];
  const float* h0 = (const float*)d_in[2];
  const float* Wi = (const float*)d_in[3];
  const float* Wh = (const float*)d_in[4];
  const float* b  = (const float*)d_in[5];
  float* out = (float*)d_out;
  char* ws = (char*)d_ws;
  unsigned short* Aws  = (unsigned short*)(ws + OFF_A);
  unsigned short* xb   = (unsigned short*)(ws + OFF_XB);
  unsigned short* wiT  = (unsigned short*)(ws + OFF_WIT);
  unsigned short* whT  = (unsigned short*)(ws + OFF_WHT);
  unsigned short* hbuf = (unsigned short*)(ws + OFF_HBUF);
  int* flags = (int*)(ws + OFF_FLAGS);

  hipMemsetAsync(flags, 0, 4096, stream);
  convert_kernel<<<4096, 256, 0, stream>>>(x, h0, xb, hbuf);
  transpose_kernel<<<dim3(128, 32), 256, 0, stream>>>(Wi, wiT);
  transpose_kernel<<<dim3(128, 32), 256, 0, stream>>>(Wh, whT);
  gemm1_kernel<<<8192, 256, 0, stream>>>(xb, wiT, b, Aws);
  lstm_kernel<<<NBLK, 256, 64 * WPITCH + 8192, stream>>>(Aws, whT, c0, hbuf, out, flags);
}